// Round 15
// baseline (251.225 us; speedup 1.0000x reference)
//
#include <hip/hip_runtime.h>
#include <stdint.h>

// ---------------------------------------------------------------------------
// AlbertDecoderAttention on MI355X (gfx950) — round 15
// Change vs round 14 (qkv only; everything else byte-identical):
//  * qkv4g: B-fragments load DIRECTLY from global (L2-hot) into registers
//    with 1-iter prefetch — B never touches LDS. Only A staged via gl_lds
//    (3-buf, swizzled, 24KB). Halves LDS pipe traffic (was the measured
//    per-CU bottleneck: 64 ds_read_b128/step ~ 768cyc vs 154cyc MFMA).
//  * tile 128x128, 4 waves, grid 768 = 3.0 blocks/CU UNIFORM (was 384 =
//    1.5/CU, 75% utilization ceiling). LDS 32KB (epilogue bounce tile).
//  * vmcnt ledger: per iter issue Bf(t+1) then stageA(t+2); VMCNT(2) at
//    iter end drains Bf(t+1), keeps stage; tail VMCNT(4)/(0).
// ---------------------------------------------------------------------------

typedef unsigned short u16;
typedef __bf16 bf16x8 __attribute__((ext_vector_type(8)));
typedef float f32x4 __attribute__((ext_vector_type(4)));

#define AS1 __attribute__((address_space(1)))
#define AS3 __attribute__((address_space(3)))
typedef AS3 char lds_char;
typedef AS3 unsigned short lds_u16;

#define VMCNT(n) asm volatile("s_waitcnt vmcnt(" #n ")" ::: "memory")
#define LGKM0() asm volatile("s_waitcnt lgkmcnt(0)" ::: "memory")
#define SBARRIER() asm volatile("s_barrier" ::: "memory")

__device__ __forceinline__ u16 f2bf(float f) {
  union { float f; uint32_t u; } v; v.f = f;
  uint32_t u = v.u;
  return (u16)((u + 0x7fffu + ((u >> 16) & 1u)) >> 16);  // RNE
}

__device__ __forceinline__ float bf2f(u16 b) {
  union { uint32_t u; float f; } v; v.u = ((uint32_t)b) << 16;
  return v.f;
}

__device__ __forceinline__ uint32_t cvt_pk_bf16(float lo, float hi) {
  uint32_t r;
  asm("v_cvt_pk_bf16_f32 %0, %1, %2" : "=v"(r) : "v"(lo), "v"(hi));
  return r;
}

__device__ __forceinline__ void gl_lds16(const void* g, void* l) {
  __builtin_amdgcn_global_load_lds((AS1 void*)(g), (AS3 void*)(l), 16, 0, 0);
}

__device__ __forceinline__ bf16x8 dsr128(const lds_u16* p) {
  bf16x8 r;
  asm volatile("ds_read_b128 %0, %1" : "=v"(r) : "v"(p));
  return r;
}

// swizzled byte address within a [rows][128B] LDS tile (attn tiles)
__device__ __forceinline__ int swz(int row, int byte) {
  return row * 128 + (byte ^ ((row & 7) << 4));
}

// ---------------------------------------------------------------------------
// f32 -> bf16 convert, two tensors in one launch (each 4096*1024 elems)
// ---------------------------------------------------------------------------
__global__ void __launch_bounds__(256)
convert2_kernel(const float* __restrict__ in0, u16* __restrict__ out0,
                const float* __restrict__ in1, u16* __restrict__ out1) {
  const int half = blockIdx.x >> 12;
  const int i = (blockIdx.x & 4095) * 256 + threadIdx.x;
  const float* in = half ? in1 : in0;
  u16* out = half ? out1 : out0;
  float4 v = ((const float4*)in)[i];
  ushort4 o;
  o.x = f2bf(v.x); o.y = f2bf(v.y); o.z = f2bf(v.z); o.w = f2bf(v.w);
  ((ushort4*)out)[i] = o;
}

// ---------------------------------------------------------------------------
// Weight transpose + convert: W[k][n] f32 -> Wt[n][k] bf16 (7 matrices)
// ---------------------------------------------------------------------------
struct WP { const float* w[7]; };

__global__ void __launch_bounds__(256)
transpose_kernel(WP wp, u16* __restrict__ out) {
  __shared__ float tile[64][65];
  const float* W = wp.w[blockIdx.z];
  u16* Wt = out + (size_t)blockIdx.z * 1024 * 1024;
  const int k0 = blockIdx.y * 64, n0 = blockIdx.x * 64;
  const int t = threadIdx.x;
  const int r = t >> 4, c4 = (t & 15) * 4;
#pragma unroll
  for (int rr = 0; rr < 64; rr += 16) {
    float4 v = *(const float4*)&W[(size_t)(k0 + r + rr) * 1024 + n0 + c4];
    tile[r + rr][c4 + 0] = v.x; tile[r + rr][c4 + 1] = v.y;
    tile[r + rr][c4 + 2] = v.z; tile[r + rr][c4 + 3] = v.w;
  }
  __syncthreads();
  const int n = t >> 2, seg = (t & 3) * 16;
  union { u16 s[16]; uint4 q[2]; } u;
#pragma unroll
  for (int i = 0; i < 16; ++i) u.s[i] = f2bf(tile[seg + i][n]);
  uint4* dst = (uint4*)&Wt[(size_t)(n0 + n) * 1024 + k0 + seg];
  dst[0] = u.q[0]; dst[1] = u.q[1];
}

// ---------------------------------------------------------------------------
// qkv4g: 3-segment projection GEMM. 128x128 tile, BK=32, 4 waves (2Mx2N),
// grid 768 (3 blocks/CU uniform). A staged in LDS (3-buf 24KB, swizzled,
// stage t+2); B-frags DIRECT from global with 1-iter register prefetch.
// 32KB LDS total (epilogue bounce tile). VMCNT(2) steady, (4)/(0) tail.
// Bt = [W0|W1|W2] as [3072][1024]. seg0->qb, seg1->kb, seg2->Vt.
// ---------------------------------------------------------------------------
__global__ void __launch_bounds__(256, 3)
qkv4g_kernel(const u16* __restrict__ A0, const u16* __restrict__ A1,
             const u16* __restrict__ A2, const u16* __restrict__ Bt,
             const float* __restrict__ b0, const float* __restrict__ b1,
             const float* __restrict__ b2,
             u16* __restrict__ qb, u16* __restrict__ kb, u16* __restrict__ vt) {
  __shared__ u16 SH[16384];   // 32KB: 3x 8KB A-buffers; epilogue 128x128 tile

  // XCD-chunked mapping: 768 blocks = 8 XCD x (8m x 12n)
  const int d = blockIdx.y * 24 + blockIdx.x;
  const int xcd = d & 7, ci = d >> 3;            // ci 0..95
  const int mt = (xcd & 3) * 8 + (ci & 7);       // 0..31
  const int nt = (xcd >> 2) * 12 + (ci >> 3);    // 0..23
  const int bm = mt * 128, bn = nt * 128;
  const int seg = nt >> 3;                        // 8 n-tiles per segment
  const int cs = (nt & 7) * 128;
  const u16* A = (seg == 0) ? A0 : (seg == 1) ? A1 : A2;

  const int t = threadIdx.x, wv = t >> 6, ln = t & 63;
  const int wm = (wv >> 1) * 64, wn = (wv & 1) * 64;
  const int lcol = ln & 15, g = ln >> 4;
  const int aoff = (g * 16) ^ (((lcol >> 1) & 3) << 4);   // 64B-row swizzle

  lds_char* base = (lds_char*)&SH[0];

  // A staging: 128 rows x 64B per buffer; 256 threads x 16B x 2 loads.
  // dest row = l*64 + wv*16 + (ln>>2), chunk (t&3); (row>>1)&3 == (t>>3)&3
  const int st_srcb = (((t & 3) ^ ((t >> 3) & 3)) * 16);
  auto stageA = [&](int buf, int k0) {
#pragma unroll
    for (int l = 0; l < 2; ++l) {
      const int row = l * 64 + (t >> 2);
      gl_lds16((const char*)A + ((size_t)(bm + row) * 1024 + k0) * 2 + st_srcb,
               (char*)base + buf * 8192 + l * 4096 + wv * 1024);
    }
  };

  // B-frag global address base: rows bn+wn+j*16+lcol, k chunk g*8
  const u16* Bbase = Bt + (size_t)(bn + wn + lcol) * 1024 + g * 8;

  f32x4 acc[4][4] = {};
  bf16x8 Bcur[4], Bnxt[4];

  // prologue: stageA(0); load Bf(0); stageA(1); VMCNT(2) leaves stageA(1)
  stageA(0, 0);
#pragma unroll
  for (int j = 0; j < 4; ++j)
    Bcur[j] = *(const bf16x8*)(Bbase + (size_t)j * 16 * 1024);
  stageA(1, 32);
  VMCNT(2);
  __builtin_amdgcn_s_barrier();

  int cur = 0, st = 2;
  for (int kt = 0; kt < 32; ++kt) {
    lds_char* Ab = base + cur * 8192;
    bf16x8 afr[4];
#pragma unroll
    for (int i = 0; i < 4; ++i)
      afr[i] = dsr128((const lds_u16*)(Ab + (wm + i * 16 + lcol) * 64 + aoff));
    if (kt < 31) {
      const int k1 = (kt + 1) * 32;
#pragma unroll
      for (int j = 0; j < 4; ++j)
        Bnxt[j] = *(const bf16x8*)(Bbase + (size_t)j * 16 * 1024 + k1);
    }
    if (kt < 30) stageA(st, (kt + 2) * 32);
    __builtin_amdgcn_s_barrier();
    if (kt == 31) VMCNT(0);           // Bf(31) landed
    LGKM0();
    __builtin_amdgcn_sched_barrier(0);
    __builtin_amdgcn_s_setprio(1);
#pragma unroll
    for (int i = 0; i < 4; ++i)
#pragma unroll
      for (int j = 0; j < 4; ++j)
        acc[i][j] = __builtin_amdgcn_mfma_f32_16x16x32_bf16(afr[i], Bcur[j], acc[i][j], 0, 0, 0);
    __builtin_amdgcn_s_setprio(0);
    if (kt < 30)       { VMCNT(2); }  // drains Bf(kt+1); leaves stageA(kt+2)
    else if (kt == 30) { VMCNT(4); }  // drains stageA(31); leaves Bf(31)
    __builtin_amdgcn_s_barrier();
#pragma unroll
    for (int j = 0; j < 4; ++j) Bcur[j] = Bnxt[j];
    cur = (cur == 2) ? 0 : cur + 1;
    st  = (st == 2)  ? 0 : st + 1;
  }

  // ---- epilogue: bounce through SH as 128x128 bf16 tile (full-line writes)
  const float* bias = (seg == 0) ? b0 : (seg == 1) ? b1 : b2;

  if (seg == 2) {
    // transposed: SH[col 128][m 128], 256B rows; byte m4*2 ^ ((col&7)<<4)
#pragma unroll
    for (int j = 0; j < 4; ++j) {
      const int col_l = wn + j * 16 + lcol;
      const float bc = bias[cs + col_l];
#pragma unroll
      for (int i = 0; i < 4; ++i) {
        const int m4 = wm + i * 16 + g * 4;
        ushort4 o;
        o.x = f2bf(acc[i][j][0] + bc); o.y = f2bf(acc[i][j][1] + bc);
        o.z = f2bf(acc[i][j][2] + bc); o.w = f2bf(acc[i][j][3] + bc);
        *(ushort4*)((char*)SH + col_l * 256 + ((m4 * 2) ^ ((col_l & 7) << 4))) = o;
      }
    }
  } else {
    // row-major: SH[m 128][col 128]; index swizzle col ^ ((m&7)<<3)
#pragma unroll
    for (int j = 0; j < 4; ++j) {
      const int col_l = wn + j * 16 + lcol;
      const float bc = bias[cs + col_l];
#pragma unroll
      for (int i = 0; i < 4; ++i) {
        const int m0 = wm + i * 16 + g * 4;
#pragma unroll
        for (int r = 0; r < 4; ++r)
          SH[(m0 + r) * 128 + (col_l ^ (((m0 + r) & 7) << 3))] = f2bf(acc[i][j][r] + bc);
      }
    }
  }
  __builtin_amdgcn_s_barrier();

  if (seg == 2) {
    // 128 cols x 256B; thread: col = t>>1, half hb = t&1 (128B)
    const int C = t >> 1, hb = t & 1;
    const int col = cs + C;
    const int h = col >> 6, dd = col & 63;
    u16* gp = vt + ((size_t)((bm >> 10) * 16 + h) * 64 + dd) * 1024 + (bm & 1023) + hb * 64;
#pragma unroll
    for (int cix = 0; cix < 8; ++cix) {
      uint4 v = *(uint4*)((char*)SH + C * 256 + ((hb * 128 + cix * 16) ^ ((C & 7) << 4)));
      *(uint4*)(gp + cix * 8) = v;
    }
  } else {
    // 128 rows x 256B; thread: row = t>>1, half hb = t&1 (128B)
    const int R = t >> 1, hb = t & 1;
    u16* outp = (seg == 0) ? qb : kb;
    u16* gp = outp + (size_t)(bm + R) * 1024 + cs + hb * 64;
#pragma unroll
    for (int cix = 0; cix < 8; ++cix) {
      uint4 v = *(uint4*)((char*)SH + R * 256 + ((hb * 128 + cix * 16) ^ ((R & 7) << 4)));
      *(uint4*)(gp + cix * 8) = v;
    }
  }
}

// ---------------------------------------------------------------------------
// Wo-projection GEMM: 128x128, BK=64, 4 waves, 3-buf stage t+2 / VMCNT(8),
// swizzled LDS (3-bit XOR), 32-MFMA barrier intervals.
// out f32 = acc + bias + bf2f(resid). XCD-chunked (8m x 4n).
// ---------------------------------------------------------------------------
__global__ void __launch_bounds__(256)
gemm_proj(const u16* __restrict__ A, const u16* __restrict__ Bt,
          const float* __restrict__ bias, const u16* __restrict__ resid,
          float* __restrict__ outf) {
  __shared__ u16 Alds[3][8192];   // 16KB each, 128B rows, swizzled
  __shared__ u16 Blds[3][8192];
  const int d = blockIdx.y * 8 + blockIdx.x;   // 256 blocks
  const int c = d & 7, ci = d >> 3;
  const int mt = (c & 3) * 8 + (ci & 7);
  const int nt = (c >> 2) * 4 + (ci >> 3);
  const int bm = mt * 128, bn = nt * 128;
  const int t = threadIdx.x, wv = t >> 6, ln = t & 63;
  const int wm = (wv >> 1) * 64, wn = (wv & 1) * 64;
  const int lcol = ln & 15, g = ln >> 4, lr4 = g * 4;
  const int xr = (lcol & 7) << 4;
  const int aoff0 = (g * 16) ^ xr;          // ks=0
  const int aoff1 = (64 + g * 16) ^ xr;     // ks=1

  f32x4 acc[4][4] = {};

  // stage: 128 rows x 128B per matrix; thread row = t>>3, chunk t&7
  const int st_srcb = (((t & 7) ^ ((t >> 3) & 7)) * 16);
  auto STAGE = [&](int buf, int k0) {
#pragma unroll
    for (int l = 0; l < 4; ++l) {
      const int row = l * 32 + (t >> 3);
      gl_lds16((const char*)A + ((size_t)(bm + row) * 1024 + k0) * 2 + st_srcb,
               (char*)&Alds[buf][0] + l * 4096 + (t >> 6) * 1024);
      gl_lds16((const char*)Bt + ((size_t)(bn + row) * 1024 + k0) * 2 + st_srcb,
               (char*)&Blds[buf][0] + l * 4096 + (t >> 6) * 1024);
    }
  };

  STAGE(0, 0);
  STAGE(1, 64);
  VMCNT(8);
  __builtin_amdgcn_s_barrier();

  int cur = 0, st = 2;
  for (int it = 0; it < 16; ++it) {
    lds_char* Ab = (lds_char*)&Alds[cur][0];
    lds_char* Bb = (lds_char*)&Blds[cur][0];
    bf16x8 a0[4], b0v[4], a1[4], b1v[4];
#pragma unroll
    for (int i = 0; i < 4; ++i) {
      a0[i]  = dsr128((const lds_u16*)(Ab + (wm + i * 16 + lcol) * 128 + aoff0));
      b0v[i] = dsr128((const lds_u16*)(Bb + (wn + i * 16 + lcol) * 128 + aoff0));
    }
#pragma unroll
    for (int i = 0; i < 4; ++i) {
      a1[i]  = dsr128((const lds_u16*)(Ab + (wm + i * 16 + lcol) * 128 + aoff1));
      b1v[i] = dsr128((const lds_u16*)(Bb + (wn + i * 16 + lcol) * 128 + aoff1));
    }
    if (it < 14) STAGE(st, (it + 2) * 64);
    __builtin_amdgcn_s_barrier();
    LGKM0();
    __builtin_amdgcn_sched_barrier(0);
    __builtin_amdgcn_s_setprio(1);
#pragma unroll
    for (int i = 0; i < 4; ++i)
#pragma unroll
      for (int j = 0; j < 4; ++j)
        acc[i][j] = __builtin_amdgcn_mfma_f32_16x16x32_bf16(a0[i], b0v[j], acc[i][j], 0, 0, 0);
#pragma unroll
    for (int i = 0; i < 4; ++i)
#pragma unroll
      for (int j = 0; j < 4; ++j)
        acc[i][j] = __builtin_amdgcn_mfma_f32_16x16x32_bf16(a1[i], b1v[j], acc[i][j], 0, 0, 0);
    __builtin_amdgcn_s_setprio(0);
    if (it < 14)       { VMCNT(8); }
    else if (it == 14) { VMCNT(0); }
    __builtin_amdgcn_s_barrier();
    cur = (cur == 2) ? 0 : cur + 1;
    st  = (st == 2)  ? 0 : st + 1;
  }

#pragma unroll
  for (int j = 0; j < 4; ++j) {
    const int col = bn + wn + j * 16 + lcol;
    const float bc = bias[col];
#pragma unroll
    for (int i = 0; i < 4; ++i) {
      const int row0 = bm + wm + i * 16 + lr4;
#pragma unroll
      for (int r = 0; r < 4; ++r) {
        const size_t idx = (size_t)(row0 + r) * 1024 + col;
        outf[idx] = acc[i][j][r] + bc + bf2f(resid[idx]);
      }
    }
  }
}

// ---------------------------------------------------------------------------
// Flash attention (round-9 verified math), swapped-QK^T, defer-max softmax,
// counted-vmcnt pipeline, global mask prefetch. 8 waves x 128 q-rows/block,
// 512 blocks (XCD-grouped), 48KB LDS -> 3 blocks/CU (24 waves/CU).
// ---------------------------------------------------------------------------
__global__ void __launch_bounds__(512)
attn_kernel(const u16* __restrict__ Q, const u16* __restrict__ Kb,
            const u16* __restrict__ Vt, const float* __restrict__ mask,
            u16* __restrict__ ctx) {
  __shared__ u16 Klds[2][64 * 64];   // [s][d], swizzled, 8KB each
  __shared__ u16 Vlds[2][64 * 64];   // [d][s], swizzled
  __shared__ u16 Plds[8][16 * 64];   // per-wave [q][s], swizzled, 16KB

  const int fid = blockIdx.x;        // 512 blocks
  const int xcd = fid & 7, idx = fid >> 3;        // idx 0..63
  const int bh = xcd * 8 + (idx >> 3);            // 8 q-blocks per (b,h), same XCD
  const int b = bh >> 4, h = bh & 15;
  const int q0 = (idx & 7) * 128;

  const int t = threadIdx.x, wv = t >> 6, ln = t & 63;
  const int lcol = ln & 15, g = ln >> 4;
  const int lk8 = g * 8, c0 = g * 16;

  const int qrow = q0 + wv * 16 + lcol;
  const u16* qptr = Q + ((size_t)(b * 1024 + qrow) * 1024 + h * 64);
  bf16x8 qa[2];
  qa[0] = *(const bf16x8*)(qptr + lk8);
  qa[1] = *(const bf16x8*)(qptr + 32 + lk8);

  const float* mrow = mask + b * 1024;
  char* pbase = (char*)&Plds[wv][0];

  f32x4 accO[4] = {};
  float m_r = -1e30f, l_r = 0.f;

  // staging: 512 threads cover 64 rows x 128B per matrix (1 K + 1 V load each)
  const int st_row = t >> 3;                               // 0..63
  const int st_srcb = (((t & 7) ^ ((t >> 3) & 7)) * 16);
  auto STAGE = [&](int buf, int s0) {
    gl_lds16((const char*)Kb + ((size_t)((b * 1024 + s0 + st_row) * 1024 + h * 64)) * 2 + st_srcb,
             (char*)Klds[buf] + wv * 1024);
    gl_lds16((const char*)Vt + ((size_t)(((b * 16 + h) * 64 + st_row) * 1024 + s0)) * 2 + st_srcb,
             (char*)Vlds[buf] + wv * 1024);
  };

  auto TILE = [&](int buf, const float4* mk) {
    f32x4 accST[4] = {};
    __builtin_amdgcn_s_setprio(1);
#pragma unroll
    for (int ks = 0; ks < 2; ++ks)
#pragma unroll
      for (int sb = 0; sb < 4; ++sb) {
        bf16x8 kb = *(const bf16x8*)((const char*)Klds[buf] + swz(sb * 16 + lcol, ks * 64 + c0));
        accST[sb] = __builtin_amdgcn_mfma_f32_16x16x32_bf16(kb, qa[ks], accST[sb], 0, 0, 0);
      }
    __builtin_amdgcn_s_setprio(0);

    float sv[4][4];
#pragma unroll
    for (int sb = 0; sb < 4; ++sb) {
      sv[sb][0] = accST[sb][0] * 0.125f + mk[sb].x;
      sv[sb][1] = accST[sb][1] * 0.125f + mk[sb].y;
      sv[sb][2] = accST[sb][2] * 0.125f + mk[sb].z;
      sv[sb][3] = accST[sb][3] * 0.125f + mk[sb].w;
    }
    float mt = sv[0][0];
#pragma unroll
    for (int sb = 0; sb < 4; ++sb)
#pragma unroll
      for (int r = 0; r < 4; ++r) mt = fmaxf(mt, sv[sb][r]);
    mt = fmaxf(mt, __shfl_xor(mt, 16));
    mt = fmaxf(mt, __shfl_xor(mt, 32));

    const bool nr = __all(mt <= m_r + 8.0f) != 0;
    float alpha = 1.0f;
    if (!nr) {
      const float mn2 = fmaxf(m_r, mt);
      alpha = __expf(m_r - mn2);
      m_r = mn2;
    }
    float rs = 0.f;
#pragma unroll
    for (int sb = 0; sb < 4; ++sb)
#pragma unroll
      for (int r = 0; r < 4; ++r) {
        const float pp = __expf(sv[sb][r] - m_r);
        sv[sb][r] = pp;
        rs += pp;
      }
    rs += __shfl_xor(rs, 16);
    rs += __shfl_xor(rs, 32);
    l_r = nr ? (l_r + rs) : (l_r * alpha + rs);

#pragma unroll
    for (int sb = 0; sb < 4; ++sb) {
      uint2 dd;
      dd.x = cvt_pk_bf16(sv[sb][0], sv[sb][1]);
      dd.y = cvt_pk_bf16(sv[sb][2], sv[sb][3]);
      *(uint2*)(pbase + swz(lcol, sb * 32 + g * 8)) = dd;
    }

    if (!nr) {
#pragma unroll
      for (int df = 0; df < 4; ++df)
#pragma unroll
        for (int r = 0; r < 4; ++r) accO[df][r] *= alpha;
    }
    __builtin_amdgcn_s_setprio(1);
#pragma unroll
    for (int ks = 0; ks < 2; ++ks) {
      bf16x8 pb = *(const bf16x8*)(pbase + swz(lcol, ks * 64 + c0));
#pragma unroll
      for (int df = 0; df < 4; ++df) {
        bf16x8 va = *(const bf16x8*)((const char*)Vlds[buf] + swz(df * 16 + lcol, ks * 64 + c0));
        accO[df] = __builtin_amdgcn_mfma_f32_16x16x32_bf16(va, pb, accO[df], 0, 0, 0);
      }
    }
    __builtin_amdgcn_s_setprio(0);
  };

  STAGE(0, 0);
  float4 mk_cur[4];
#pragma unroll
  for (int sb = 0; sb < 4; ++sb)
    mk_cur[sb] = *(const float4*)&mrow[sb * 16 + g * 4];

  int cur = 0;
  for (int ti = 0; ti < 15; ++ti) {
    const int s1 = ti * 64 + 64;
    STAGE(cur ^ 1, s1);
    float4 mk_nxt[4];
#pragma unroll
    for (int sb = 0; sb < 4; ++sb)
      mk_nxt[sb] = *(const float4*)&mrow[s1 + sb * 16 + g * 4];
    VMCNT(10);         // drains tile ti's 2 stage loads; ti+1's stay in flight
    SBARRIER();
    TILE(cur, mk_cur);
    SBARRIER();
#pragma unroll
    for (int sb = 0; sb < 4; ++sb) mk_cur[sb] = mk_nxt[sb];
    cur ^= 1;
  }
  VMCNT(4);            // last tile's 2 stage loads landed (masks may fly)
  SBARRIER();
  TILE(cur, mk_cur);

  const float inv = 1.0f / l_r;
  u16* cp = ctx + ((size_t)(b * 1024 + qrow) * 1024 + h * 64);
#pragma unroll
  for (int df = 0; df < 4; ++df) {
    ushort4 o;
    o.x = f2bf(accO[df][0] * inv); o.y = f2bf(accO[df][1] * inv);
    o.z = f2bf(accO[df][2] * inv); o.w = f2bf(accO[df][3] * inv);
    *(ushort4*)(cp + df * 16 + g * 4) = o;
  }
}

// ---------------------------------------------------------------------------
// LayerNorm over rows of x[4096][1024]; OUTF=1 -> f32 out, else bf16 out
// ---------------------------------------------------------------------------
template <int OUTF>
__global__ void __launch_bounds__(256)
ln_kernel(const float* __restrict__ x, const float* __restrict__ gamma,
          const float* __restrict__ beta, float* __restrict__ outf,
          u16* __restrict__ outb) {
  const int row = blockIdx.x, t = threadIdx.x;
  const float* xr = x + (size_t)row * 1024;
  float4 v = *(const float4*)&xr[t * 4];
  float s = v.x + v.y + v.z + v.w;
  float q = v.x * v.x + v.y * v.y + v.z * v.z + v.w * v.w;
#pragma unroll
  for (int off = 1; off < 64; off <<= 1) {
    s += __shfl_xor(s, off);
    q += __shfl_xor(q, off);
  }
  __shared__ float ws[4], wq[4];
  if ((t & 63) == 0) { ws[t >> 6] = s; wq[t >> 6] = q; }
  __syncthreads();
  s = ws[0] + ws[1] + ws[2] + ws[3];
  q = wq[0] + wq[1] + wq[2] + wq[3];
  const float mu = s * (1.0f / 1024.0f);
  float var = q * (1.0f / 1024.0f) - mu * mu;
  var = fmaxf(var, 0.0f);
  const float rstd = rsqrtf(var + 1e-12f);
  float4 g = *(const float4*)&gamma[t * 4];
  float4 be = *(const float4*)&beta[t * 4];
  float y0 = (v.x - mu) * rstd * g.x + be.x;
  float y1 = (v.y - mu) * rstd * g.y + be.y;
  float y2 = (v.z - mu) * rstd * g.z + be.z;
  float y3 = (v.w - mu) * rstd * g.w + be.w;
  if constexpr (OUTF) {
    float4 o; o.x = y0; o.y = y1; o.z = y2; o.w = y3;
    *(float4*)&outf[(size_t)row * 1024 + t * 4] = o;
  } else {
    ushort4 o; o.x = f2bf(y0); o.y = f2bf(y1); o.z = f2bf(y2); o.w = f2bf(y3);
    *(ushort4*)&outb[(size_t)row * 1024 + t * 4] = o;
  }
}

// ---------------------------------------------------------------------------
extern "C" void kernel_launch(void* const* d_in, const int* in_sizes, int n_in,
                              void* d_out, int out_size, void* d_ws, size_t ws_size,
                              hipStream_t stream) {
  const float* enc = (const float*)d_in[0];
  const float* dec = (const float*)d_in[1];
  const float* src_mask = (const float*)d_in[2];
  const float* tgt_mask = (const float*)d_in[3];
  const float* Wq  = (const float*)d_in[4];  const float* bq  = (const float*)d_in[5];
  const float* Wk  = (const float*)d_in[6];  const float* bk  = (const float*)d_in[7];
  const float* Wv  = (const float*)d_in[8];  const float* bv  = (const float*)d_in[9];
  const float* Wq2 = (const float*)d_in[10]; const float* bq2 = (const float*)d_in[11];
  const float* Wk2 = (const float*)d_in[12]; const float* bk2 = (const float*)d_in[13];
  const float* Wv2 = (const float*)d_in[14]; const float* bv2 = (const float*)d_in[15];
  const float* Wo  = (const float*)d_in[16]; const float* bo  = (const float*)d_in[17];
  const float* gamma = (const float*)d_in[18]; const float* beta = (const float*)d_in[19];
  float* out = (float*)d_out;

  char* p = (char*)d_ws;
  const size_t ABF = (size_t)4096 * 1024 * 2;
  const size_t AF  = (size_t)4096 * 1024 * 4;
  const size_t WBF = (size_t)1024 * 1024 * 2;
  u16* decbf = (u16*)p; p += ABF;
  u16* encbf = (u16*)p; p += ABF;
  u16* wt    = (u16*)p; p += 7 * WBF;
  u16* qbf   = (u16*)p; p += ABF;
  u16* kbf   = (u16*)p; p += ABF;
  u16* vtb   = (u16*)p; p += ABF;
  u16* ctxb  = (u16*)p; p += ABF;
  float* tmpf = (float*)p; p += AF;
  u16* sobf  = decbf;  // reuse: decoder bf16 dead after layer-1 projections

  u16* WoT  = wt + 6 * 1048576;

  dim3 b256(256);
  convert2_kernel<<<8192, b256, 0, stream>>>(dec, decbf, enc, encbf);
  WP wp;
  wp.w[0] = Wq; wp.w[1] = Wk; wp.w[2] = Wv; wp.w[3] = Wq2;
  wp.w[4] = Wk2; wp.w[5] = Wv2; wp.w[6] = Wo;
  transpose_kernel<<<dim3(16, 16, 7), b256, 0, stream>>>(wp, wt);

  // ---- layer 1 (self-attention on decoder inputs) ----
  qkv4g_kernel<<<dim3(24, 32), b256, 0, stream>>>(
      decbf, decbf, decbf, wt, bq, bk, bv, qbf, kbf, vtb);
  attn_kernel<<<512, 512, 0, stream>>>(qbf, kbf, vtb, tgt_mask, ctxb);
  gemm_proj<<<dim3(8, 32), b256, 0, stream>>>(ctxb, WoT, bo, qbf, tmpf);
  ln_kernel<0><<<4096, b256, 0, stream>>>(tmpf, gamma, beta, nullptr, sobf);
  // ---- layer 2 (cross-attention vs encoder states) ----
  qkv4g_kernel<<<dim3(24, 32), b256, 0, stream>>>(
      sobf, encbf, encbf, wt + 3 * 1048576, bq2, bk2, bv2, qbf, kbf, vtb);
  attn_kernel<<<512, 512, 0, stream>>>(qbf, kbf, vtb, src_mask, ctxb);
  gemm_proj<<<dim3(8, 32), b256, 0, stream>>>(ctxb, WoT, bo, qbf, tmpf);
  ln_kernel<1><<<4096, b256, 0, stream>>>(tmpf, gamma, beta, out, nullptr);
}

// Round 16
// 207.534 us; speedup vs baseline: 1.2105x; 1.2105x over previous
//
#include <hip/hip_runtime.h>
#include <stdint.h>

// ---------------------------------------------------------------------------
// AlbertDecoderAttention on MI355X (gfx950) — round 16
// Change vs round 14 (qkv only; attn/gemm_proj/ln/converts = round 14):
//  * qkv3c: 128x128 tile, 4 waves (2Mx2N), BK=32, A+B LDS-staged 3-buf
//    (48KB -> 3 blocks/CU), grid 768 = 3.0 blocks/CU UNIFORM (round 14's
//    384 = 1.5/CU had a 75% utilization ceiling). Stage t+2, VMCNT(4)
//    steady / (0) tail. Proven swizzle + LDS-bounce epilogue.
//  * round 15's B-direct-global experiment reverted (uncoalesced 2KB-stride
//    lane reads regressed 41 -> 66 us).
// ---------------------------------------------------------------------------

typedef unsigned short u16;
typedef __bf16 bf16x8 __attribute__((ext_vector_type(8)));
typedef float f32x4 __attribute__((ext_vector_type(4)));

#define AS1 __attribute__((address_space(1)))
#define AS3 __attribute__((address_space(3)))
typedef AS3 char lds_char;
typedef AS3 unsigned short lds_u16;

#define VMCNT(n) asm volatile("s_waitcnt vmcnt(" #n ")" ::: "memory")
#define LGKM0() asm volatile("s_waitcnt lgkmcnt(0)" ::: "memory")
#define SBARRIER() asm volatile("s_barrier" ::: "memory")

__device__ __forceinline__ u16 f2bf(float f) {
  union { float f; uint32_t u; } v; v.f = f;
  uint32_t u = v.u;
  return (u16)((u + 0x7fffu + ((u >> 16) & 1u)) >> 16);  // RNE
}

__device__ __forceinline__ float bf2f(u16 b) {
  union { uint32_t u; float f; } v; v.u = ((uint32_t)b) << 16;
  return v.f;
}

__device__ __forceinline__ uint32_t cvt_pk_bf16(float lo, float hi) {
  uint32_t r;
  asm("v_cvt_pk_bf16_f32 %0, %1, %2" : "=v"(r) : "v"(lo), "v"(hi));
  return r;
}

__device__ __forceinline__ void gl_lds16(const void* g, void* l) {
  __builtin_amdgcn_global_load_lds((AS1 void*)(g), (AS3 void*)(l), 16, 0, 0);
}

__device__ __forceinline__ bf16x8 dsr128(const lds_u16* p) {
  bf16x8 r;
  asm volatile("ds_read_b128 %0, %1" : "=v"(r) : "v"(p));
  return r;
}

// swizzled byte address within a [rows][128B] LDS tile (attn tiles)
__device__ __forceinline__ int swz(int row, int byte) {
  return row * 128 + (byte ^ ((row & 7) << 4));
}

// ---------------------------------------------------------------------------
// f32 -> bf16 convert, two tensors in one launch (each 4096*1024 elems)
// ---------------------------------------------------------------------------
__global__ void __launch_bounds__(256)
convert2_kernel(const float* __restrict__ in0, u16* __restrict__ out0,
                const float* __restrict__ in1, u16* __restrict__ out1) {
  const int half = blockIdx.x >> 12;
  const int i = (blockIdx.x & 4095) * 256 + threadIdx.x;
  const float* in = half ? in1 : in0;
  u16* out = half ? out1 : out0;
  float4 v = ((const float4*)in)[i];
  ushort4 o;
  o.x = f2bf(v.x); o.y = f2bf(v.y); o.z = f2bf(v.z); o.w = f2bf(v.w);
  ((ushort4*)out)[i] = o;
}

// ---------------------------------------------------------------------------
// Weight transpose + convert: W[k][n] f32 -> Wt[n][k] bf16 (7 matrices)
// ---------------------------------------------------------------------------
struct WP { const float* w[7]; };

__global__ void __launch_bounds__(256)
transpose_kernel(WP wp, u16* __restrict__ out) {
  __shared__ float tile[64][65];
  const float* W = wp.w[blockIdx.z];
  u16* Wt = out + (size_t)blockIdx.z * 1024 * 1024;
  const int k0 = blockIdx.y * 64, n0 = blockIdx.x * 64;
  const int t = threadIdx.x;
  const int r = t >> 4, c4 = (t & 15) * 4;
#pragma unroll
  for (int rr = 0; rr < 64; rr += 16) {
    float4 v = *(const float4*)&W[(size_t)(k0 + r + rr) * 1024 + n0 + c4];
    tile[r + rr][c4 + 0] = v.x; tile[r + rr][c4 + 1] = v.y;
    tile[r + rr][c4 + 2] = v.z; tile[r + rr][c4 + 3] = v.w;
  }
  __syncthreads();
  const int n = t >> 2, seg = (t & 3) * 16;
  union { u16 s[16]; uint4 q[2]; } u;
#pragma unroll
  for (int i = 0; i < 16; ++i) u.s[i] = f2bf(tile[seg + i][n]);
  uint4* dst = (uint4*)&Wt[(size_t)(n0 + n) * 1024 + k0 + seg];
  dst[0] = u.q[0]; dst[1] = u.q[1];
}

// ---------------------------------------------------------------------------
// qkv3c: 3-segment projection GEMM. 128x128 tile, BK=32, 4 waves (2Mx2N),
// 3-buffer LDS (48KB -> 3 blocks/CU), grid 768 (3/CU uniform), stage t+2,
// VMCNT(4) steady. LDS rows 64B; swizzle byte ^= ((row>>1)&3)<<4.
// LDS-bounce epilogue. Bt = [W0|W1|W2]. seg0->qb, seg1->kb, seg2->Vt.
// ---------------------------------------------------------------------------
__global__ void __launch_bounds__(256, 3)
qkv3c_kernel(const u16* __restrict__ A0, const u16* __restrict__ A1,
             const u16* __restrict__ A2, const u16* __restrict__ Bt,
             const float* __restrict__ b0, const float* __restrict__ b1,
             const float* __restrict__ b2,
             u16* __restrict__ qb, u16* __restrict__ kb, u16* __restrict__ vt) {
  __shared__ u16 SH[24576];   // 48KB: 3 x (A 8KB | B 8KB); epilogue 32KB tile

  // XCD-chunked mapping: 768 blocks = 8 XCD x (8m x 12n)
  const int d = blockIdx.y * 24 + blockIdx.x;
  const int xcd = d & 7, ci = d >> 3;            // ci 0..95
  const int mt = (xcd & 3) * 8 + (ci & 7);       // 0..31
  const int nt = (xcd >> 2) * 12 + (ci >> 3);    // 0..23
  const int bm = mt * 128, bn = nt * 128;
  const int seg = nt >> 3;                        // 8 n-tiles per segment
  const int cs = (nt & 7) * 128;
  const u16* A = (seg == 0) ? A0 : (seg == 1) ? A1 : A2;

  const int t = threadIdx.x, wv = t >> 6, ln = t & 63;
  const int wm = (wv >> 1) * 64, wn = (wv & 1) * 64;
  const int lcol = ln & 15, g = ln >> 4;
  const int aoff = (g * 16) ^ (((lcol >> 1) & 3) << 4);   // 64B-row swizzle

  lds_char* base = (lds_char*)&SH[0];

  // staging: A,B each 128 rows x 64B; 2 gl_lds per matrix (4 total/stage).
  // dest row = l*64 + wv*16 + (ln>>2), chunk ln&3; (row>>1)&3 == (t>>3)&3
  const int st_srcb = (((t & 3) ^ ((t >> 3) & 3)) * 16);
  auto STAGE = [&](int buf, int k0) {
#pragma unroll
    for (int l = 0; l < 2; ++l) {
      const int row = l * 64 + (t >> 2);
      gl_lds16((const char*)A + ((size_t)(bm + row) * 1024 + k0) * 2 + st_srcb,
               (char*)base + buf * 16384 + l * 4096 + wv * 1024);
      gl_lds16((const char*)Bt + ((size_t)(bn + row) * 1024 + k0) * 2 + st_srcb,
               (char*)base + buf * 16384 + 8192 + l * 4096 + wv * 1024);
    }
  };

  f32x4 acc[4][4] = {};

  // prologue: stage tiles 0,1; wait tile 0 (tile 1's 4 loads in flight)
  STAGE(0, 0);
  STAGE(1, 32);
  VMCNT(4);
  __builtin_amdgcn_s_barrier();

  int cur = 0, st = 2;
  for (int kt = 0; kt < 32; ++kt) {
    lds_char* Ab = base + cur * 16384;
    lds_char* Bb = Ab + 8192;
    bf16x8 afr[4], bfr[4];
#pragma unroll
    for (int j = 0; j < 4; ++j)
      bfr[j] = dsr128((const lds_u16*)(Bb + (wn + j * 16 + lcol) * 64 + aoff));
#pragma unroll
    for (int i = 0; i < 4; ++i)
      afr[i] = dsr128((const lds_u16*)(Ab + (wm + i * 16 + lcol) * 64 + aoff));
    if (kt < 30) STAGE(st, (kt + 2) * 32);
    __builtin_amdgcn_s_barrier();
    LGKM0();
    __builtin_amdgcn_sched_barrier(0);
    __builtin_amdgcn_s_setprio(1);
#pragma unroll
    for (int i = 0; i < 4; ++i)
#pragma unroll
      for (int j = 0; j < 4; ++j)
        acc[i][j] = __builtin_amdgcn_mfma_f32_16x16x32_bf16(afr[i], bfr[j], acc[i][j], 0, 0, 0);
    __builtin_amdgcn_s_setprio(0);
    if (kt < 30)       { VMCNT(4); }   // tile kt+1 landed; kt+2 in flight
    else if (kt == 30) { VMCNT(0); }   // tile 31 landed
    __builtin_amdgcn_s_barrier();
    cur = (cur == 2) ? 0 : cur + 1;
    st  = (st == 2)  ? 0 : st + 1;
  }

  // ---- epilogue: bounce through SH as 128x128 bf16 tile (full-line writes)
  const float* bias = (seg == 0) ? b0 : (seg == 1) ? b1 : b2;

  if (seg == 2) {
    // transposed: SH[col 128][m 128], 256B rows; byte m4*2 ^ ((col&7)<<4)
#pragma unroll
    for (int j = 0; j < 4; ++j) {
      const int col_l = wn + j * 16 + lcol;
      const float bc = bias[cs + col_l];
#pragma unroll
      for (int i = 0; i < 4; ++i) {
        const int m4 = wm + i * 16 + g * 4;
        ushort4 o;
        o.x = f2bf(acc[i][j][0] + bc); o.y = f2bf(acc[i][j][1] + bc);
        o.z = f2bf(acc[i][j][2] + bc); o.w = f2bf(acc[i][j][3] + bc);
        *(ushort4*)((char*)SH + col_l * 256 + ((m4 * 2) ^ ((col_l & 7) << 4))) = o;
      }
    }
  } else {
    // row-major: SH[m 128][col 128]; index swizzle col ^ ((m&7)<<3)
#pragma unroll
    for (int j = 0; j < 4; ++j) {
      const int col_l = wn + j * 16 + lcol;
      const float bc = bias[cs + col_l];
#pragma unroll
      for (int i = 0; i < 4; ++i) {
        const int m0 = wm + i * 16 + g * 4;
#pragma unroll
        for (int r = 0; r < 4; ++r)
          SH[(m0 + r) * 128 + (col_l ^ (((m0 + r) & 7) << 3))] = f2bf(acc[i][j][r] + bc);
      }
    }
  }
  __builtin_amdgcn_s_barrier();

  if (seg == 2) {
    // 128 cols x 256B; thread: col = t>>1, half hb = t&1 (128B)
    const int C = t >> 1, hb = t & 1;
    const int col = cs + C;
    const int h = col >> 6, dd = col & 63;
    u16* gp = vt + ((size_t)((bm >> 10) * 16 + h) * 64 + dd) * 1024 + (bm & 1023) + hb * 64;
#pragma unroll
    for (int cix = 0; cix < 8; ++cix) {
      uint4 v = *(uint4*)((char*)SH + C * 256 + ((hb * 128 + cix * 16) ^ ((C & 7) << 4)));
      *(uint4*)(gp + cix * 8) = v;
    }
  } else {
    // 128 rows x 256B; thread: row = t>>1, half hb = t&1 (128B)
    const int R = t >> 1, hb = t & 1;
    u16* outp = (seg == 0) ? qb : kb;
    u16* gp = outp + (size_t)(bm + R) * 1024 + cs + hb * 64;
#pragma unroll
    for (int cix = 0; cix < 8; ++cix) {
      uint4 v = *(uint4*)((char*)SH + R * 256 + ((hb * 128 + cix * 16) ^ ((R & 7) << 4)));
      *(uint4*)(gp + cix * 8) = v;
    }
  }
}

// ---------------------------------------------------------------------------
// Wo-projection GEMM: 128x128, BK=64, 4 waves, 3-buf stage t+2 / VMCNT(8),
// swizzled LDS (3-bit XOR), 32-MFMA barrier intervals.
// out f32 = acc + bias + bf2f(resid). XCD-chunked (8m x 4n).
// ---------------------------------------------------------------------------
__global__ void __launch_bounds__(256)
gemm_proj(const u16* __restrict__ A, const u16* __restrict__ Bt,
          const float* __restrict__ bias, const u16* __restrict__ resid,
          float* __restrict__ outf) {
  __shared__ u16 Alds[3][8192];   // 16KB each, 128B rows, swizzled
  __shared__ u16 Blds[3][8192];
  const int d = blockIdx.y * 8 + blockIdx.x;   // 256 blocks
  const int c = d & 7, ci = d >> 3;
  const int mt = (c & 3) * 8 + (ci & 7);
  const int nt = (c >> 2) * 4 + (ci >> 3);
  const int bm = mt * 128, bn = nt * 128;
  const int t = threadIdx.x, wv = t >> 6, ln = t & 63;
  const int wm = (wv >> 1) * 64, wn = (wv & 1) * 64;
  const int lcol = ln & 15, g = ln >> 4, lr4 = g * 4;
  const int xr = (lcol & 7) << 4;
  const int aoff0 = (g * 16) ^ xr;          // ks=0
  const int aoff1 = (64 + g * 16) ^ xr;     // ks=1

  f32x4 acc[4][4] = {};

  // stage: 128 rows x 128B per matrix; thread row = t>>3, chunk t&7
  const int st_srcb = (((t & 7) ^ ((t >> 3) & 7)) * 16);
  auto STAGE = [&](int buf, int k0) {
#pragma unroll
    for (int l = 0; l < 4; ++l) {
      const int row = l * 32 + (t >> 3);
      gl_lds16((const char*)A + ((size_t)(bm + row) * 1024 + k0) * 2 + st_srcb,
               (char*)&Alds[buf][0] + l * 4096 + (t >> 6) * 1024);
      gl_lds16((const char*)Bt + ((size_t)(bn + row) * 1024 + k0) * 2 + st_srcb,
               (char*)&Blds[buf][0] + l * 4096 + (t >> 6) * 1024);
    }
  };

  STAGE(0, 0);
  STAGE(1, 64);
  VMCNT(8);
  __builtin_amdgcn_s_barrier();

  int cur = 0, st = 2;
  for (int it = 0; it < 16; ++it) {
    lds_char* Ab = (lds_char*)&Alds[cur][0];
    lds_char* Bb = (lds_char*)&Blds[cur][0];
    bf16x8 a0[4], b0v[4], a1[4], b1v[4];
#pragma unroll
    for (int i = 0; i < 4; ++i) {
      a0[i]  = dsr128((const lds_u16*)(Ab + (wm + i * 16 + lcol) * 128 + aoff0));
      b0v[i] = dsr128((const lds_u16*)(Bb + (wn + i * 16 + lcol) * 128 + aoff0));
    }
#pragma unroll
    for (int i = 0; i < 4; ++i) {
      a1[i]  = dsr128((const lds_u16*)(Ab + (wm + i * 16 + lcol) * 128 + aoff1));
      b1v[i] = dsr128((const lds_u16*)(Bb + (wn + i * 16 + lcol) * 128 + aoff1));
    }
    if (it < 14) STAGE(st, (it + 2) * 64);
    __builtin_amdgcn_s_barrier();
    LGKM0();
    __builtin_amdgcn_sched_barrier(0);
    __builtin_amdgcn_s_setprio(1);
#pragma unroll
    for (int i = 0; i < 4; ++i)
#pragma unroll
      for (int j = 0; j < 4; ++j)
        acc[i][j] = __builtin_amdgcn_mfma_f32_16x16x32_bf16(a0[i], b0v[j], acc[i][j], 0, 0, 0);
#pragma unroll
    for (int i = 0; i < 4; ++i)
#pragma unroll
      for (int j = 0; j < 4; ++j)
        acc[i][j] = __builtin_amdgcn_mfma_f32_16x16x32_bf16(a1[i], b1v[j], acc[i][j], 0, 0, 0);
    __builtin_amdgcn_s_setprio(0);
    if (it < 14)       { VMCNT(8); }
    else if (it == 14) { VMCNT(0); }
    __builtin_amdgcn_s_barrier();
    cur = (cur == 2) ? 0 : cur + 1;
    st  = (st == 2)  ? 0 : st + 1;
  }

#pragma unroll
  for (int j = 0; j < 4; ++j) {
    const int col = bn + wn + j * 16 + lcol;
    const float bc = bias[col];
#pragma unroll
    for (int i = 0; i < 4; ++i) {
      const int row0 = bm + wm + i * 16 + lr4;
#pragma unroll
      for (int r = 0; r < 4; ++r) {
        const size_t idx = (size_t)(row0 + r) * 1024 + col;
        outf[idx] = acc[i][j][r] + bc + bf2f(resid[idx]);
      }
    }
  }
}

// ---------------------------------------------------------------------------
// Flash attention (round-9 verified math), swapped-QK^T, defer-max softmax,
// counted-vmcnt pipeline, global mask prefetch. 8 waves x 128 q-rows/block,
// 512 blocks (XCD-grouped), 48KB LDS -> 3 blocks/CU (24 waves/CU).
// ---------------------------------------------------------------------------
__global__ void __launch_bounds__(512)
attn_kernel(const u16* __restrict__ Q, const u16* __restrict__ Kb,
            const u16* __restrict__ Vt, const float* __restrict__ mask,
            u16* __restrict__ ctx) {
  __shared__ u16 Klds[2][64 * 64];   // [s][d], swizzled, 8KB each
  __shared__ u16 Vlds[2][64 * 64];   // [d][s], swizzled
  __shared__ u16 Plds[8][16 * 64];   // per-wave [q][s], swizzled, 16KB

  const int fid = blockIdx.x;        // 512 blocks
  const int xcd = fid & 7, idx = fid >> 3;        // idx 0..63
  const int bh = xcd * 8 + (idx >> 3);            // 8 q-blocks per (b,h), same XCD
  const int b = bh >> 4, h = bh & 15;
  const int q0 = (idx & 7) * 128;

  const int t = threadIdx.x, wv = t >> 6, ln = t & 63;
  const int lcol = ln & 15, g = ln >> 4;
  const int lk8 = g * 8, c0 = g * 16;

  const int qrow = q0 + wv * 16 + lcol;
  const u16* qptr = Q + ((size_t)(b * 1024 + qrow) * 1024 + h * 64);
  bf16x8 qa[2];
  qa[0] = *(const bf16x8*)(qptr + lk8);
  qa[1] = *(const bf16x8*)(qptr + 32 + lk8);

  const float* mrow = mask + b * 1024;
  char* pbase = (char*)&Plds[wv][0];

  f32x4 accO[4] = {};
  float m_r = -1e30f, l_r = 0.f;

  // staging: 512 threads cover 64 rows x 128B per matrix (1 K + 1 V load each)
  const int st_row = t >> 3;                               // 0..63
  const int st_srcb = (((t & 7) ^ ((t >> 3) & 7)) * 16);
  auto STAGE = [&](int buf, int s0) {
    gl_lds16((const char*)Kb + ((size_t)((b * 1024 + s0 + st_row) * 1024 + h * 64)) * 2 + st_srcb,
             (char*)Klds[buf] + wv * 1024);
    gl_lds16((const char*)Vt + ((size_t)(((b * 16 + h) * 64 + st_row) * 1024 + s0)) * 2 + st_srcb,
             (char*)Vlds[buf] + wv * 1024);
  };

  auto TILE = [&](int buf, const float4* mk) {
    f32x4 accST[4] = {};
    __builtin_amdgcn_s_setprio(1);
#pragma unroll
    for (int ks = 0; ks < 2; ++ks)
#pragma unroll
      for (int sb = 0; sb < 4; ++sb) {
        bf16x8 kb = *(const bf16x8*)((const char*)Klds[buf] + swz(sb * 16 + lcol, ks * 64 + c0));
        accST[sb] = __builtin_amdgcn_mfma_f32_16x16x32_bf16(kb, qa[ks], accST[sb], 0, 0, 0);
      }
    __builtin_amdgcn_s_setprio(0);

    float sv[4][4];
#pragma unroll
    for (int sb = 0; sb < 4; ++sb) {
      sv[sb][0] = accST[sb][0] * 0.125f + mk[sb].x;
      sv[sb][1] = accST[sb][1] * 0.125f + mk[sb].y;
      sv[sb][2] = accST[sb][2] * 0.125f + mk[sb].z;
      sv[sb][3] = accST[sb][3] * 0.125f + mk[sb].w;
    }
    float mt = sv[0][0];
#pragma unroll
    for (int sb = 0; sb < 4; ++sb)
#pragma unroll
      for (int r = 0; r < 4; ++r) mt = fmaxf(mt, sv[sb][r]);
    mt = fmaxf(mt, __shfl_xor(mt, 16));
    mt = fmaxf(mt, __shfl_xor(mt, 32));

    const bool nr = __all(mt <= m_r + 8.0f) != 0;
    float alpha = 1.0f;
    if (!nr) {
      const float mn2 = fmaxf(m_r, mt);
      alpha = __expf(m_r - mn2);
      m_r = mn2;
    }
    float rs = 0.f;
#pragma unroll
    for (int sb = 0; sb < 4; ++sb)
#pragma unroll
      for (int r = 0; r < 4; ++r) {
        const float pp = __expf(sv[sb][r] - m_r);
        sv[sb][r] = pp;
        rs += pp;
      }
    rs += __shfl_xor(rs, 16);
    rs += __shfl_xor(rs, 32);
    l_r = nr ? (l_r + rs) : (l_r * alpha + rs);

#pragma unroll
    for (int sb = 0; sb < 4; ++sb) {
      uint2 dd;
      dd.x = cvt_pk_bf16(sv[sb][0], sv[sb][1]);
      dd.y = cvt_pk_bf16(sv[sb][2], sv[sb][3]);
      *(uint2*)(pbase + swz(lcol, sb * 32 + g * 8)) = dd;
    }

    if (!nr) {
#pragma unroll
      for (int df = 0; df < 4; ++df)
#pragma unroll
        for (int r = 0; r < 4; ++r) accO[df][r] *= alpha;
    }
    __builtin_amdgcn_s_setprio(1);
#pragma unroll
    for (int ks = 0; ks < 2; ++ks) {
      bf16x8 pb = *(const bf16x8*)(pbase + swz(lcol, ks * 64 + c0));
#pragma unroll
      for (int df = 0; df < 4; ++df) {
        bf16x8 va = *(const bf16x8*)((const char*)Vlds[buf] + swz(df * 16 + lcol, ks * 64 + c0));
        accO[df] = __builtin_amdgcn_mfma_f32_16x16x32_bf16(va, pb, accO[df], 0, 0, 0);
      }
    }
    __builtin_amdgcn_s_setprio(0);
  };

  STAGE(0, 0);
  float4 mk_cur[4];
#pragma unroll
  for (int sb = 0; sb < 4; ++sb)
    mk_cur[sb] = *(const float4*)&mrow[sb * 16 + g * 4];

  int cur = 0;
  for (int ti = 0; ti < 15; ++ti) {
    const int s1 = ti * 64 + 64;
    STAGE(cur ^ 1, s1);
    float4 mk_nxt[4];
#pragma unroll
    for (int sb = 0; sb < 4; ++sb)
      mk_nxt[sb] = *(const float4*)&mrow[s1 + sb * 16 + g * 4];
    VMCNT(10);         // drains tile ti's 2 stage loads; ti+1's stay in flight
    SBARRIER();
    TILE(cur, mk_cur);
    SBARRIER();
#pragma unroll
    for (int sb = 0; sb < 4; ++sb) mk_cur[sb] = mk_nxt[sb];
    cur ^= 1;
  }
  VMCNT(4);            // last tile's 2 stage loads landed (masks may fly)
  SBARRIER();
  TILE(cur, mk_cur);

  const float inv = 1.0f / l_r;
  u16* cp = ctx + ((size_t)(b * 1024 + qrow) * 1024 + h * 64);
#pragma unroll
  for (int df = 0; df < 4; ++df) {
    ushort4 o;
    o.x = f2bf(accO[df][0] * inv); o.y = f2bf(accO[df][1] * inv);
    o.z = f2bf(accO[df][2] * inv); o.w = f2bf(accO[df][3] * inv);
    *(ushort4*)(cp + df * 16 + g * 4) = o;
  }
}

// ---------------------------------------------------------------------------
// LayerNorm over rows of x[4096][1024]; OUTF=1 -> f32 out, else bf16 out
// ---------------------------------------------------------------------------
template <int OUTF>
__global__ void __launch_bounds__(256)
ln_kernel(const float* __restrict__ x, const float* __restrict__ gamma,
          const float* __restrict__ beta, float* __restrict__ outf,
          u16* __restrict__ outb) {
  const int row = blockIdx.x, t = threadIdx.x;
  const float* xr = x + (size_t)row * 1024;
  float4 v = *(const float4*)&xr[t * 4];
  float s = v.x + v.y + v.z + v.w;
  float q = v.x * v.x + v.y * v.y + v.z * v.z + v.w * v.w;
#pragma unroll
  for (int off = 1; off < 64; off <<= 1) {
    s += __shfl_xor(s, off);
    q += __shfl_xor(q, off);
  }
  __shared__ float ws[4], wq[4];
  if ((t & 63) == 0) { ws[t >> 6] = s; wq[t >> 6] = q; }
  __syncthreads();
  s = ws[0] + ws[1] + ws[2] + ws[3];
  q = wq[0] + wq[1] + wq[2] + wq[3];
  const float mu = s * (1.0f / 1024.0f);
  float var = q * (1.0f / 1024.0f) - mu * mu;
  var = fmaxf(var, 0.0f);
  const float rstd = rsqrtf(var + 1e-12f);
  float4 g = *(const float4*)&gamma[t * 4];
  float4 be = *(const float4*)&beta[t * 4];
  float y0 = (v.x - mu) * rstd * g.x + be.x;
  float y1 = (v.y - mu) * rstd * g.y + be.y;
  float y2 = (v.z - mu) * rstd * g.z + be.z;
  float y3 = (v.w - mu) * rstd * g.w + be.w;
  if constexpr (OUTF) {
    float4 o; o.x = y0; o.y = y1; o.z = y2; o.w = y3;
    *(float4*)&outf[(size_t)row * 1024 + t * 4] = o;
  } else {
    ushort4 o; o.x = f2bf(y0); o.y = f2bf(y1); o.z = f2bf(y2); o.w = f2bf(y3);
    *(ushort4*)&outb[(size_t)row * 1024 + t * 4] = o;
  }
}

// ---------------------------------------------------------------------------
extern "C" void kernel_launch(void* const* d_in, const int* in_sizes, int n_in,
                              void* d_out, int out_size, void* d_ws, size_t ws_size,
                              hipStream_t stream) {
  const float* enc = (const float*)d_in[0];
  const float* dec = (const float*)d_in[1];
  const float* src_mask = (const float*)d_in[2];
  const float* tgt_mask = (const float*)d_in[3];
  const float* Wq  = (const float*)d_in[4];  const float* bq  = (const float*)d_in[5];
  const float* Wk  = (const float*)d_in[6];  const float* bk  = (const float*)d_in[7];
  const float* Wv  = (const float*)d_in[8];  const float* bv  = (const float*)d_in[9];
  const float* Wq2 = (const float*)d_in[10]; const float* bq2 = (const float*)d_in[11];
  const float* Wk2 = (const float*)d_in[12]; const float* bk2 = (const float*)d_in[13];
  const float* Wv2 = (const float*)d_in[14]; const float* bv2 = (const float*)d_in[15];
  const float* Wo  = (const float*)d_in[16]; const float* bo  = (const float*)d_in[17];
  const float* gamma = (const float*)d_in[18]; const float* beta = (const float*)d_in[19];
  float* out = (float*)d_out;

  char* p = (char*)d_ws;
  const size_t ABF = (size_t)4096 * 1024 * 2;
  const size_t AF  = (size_t)4096 * 1024 * 4;
  const size_t WBF = (size_t)1024 * 1024 * 2;
  u16* decbf = (u16*)p; p += ABF;
  u16* encbf = (u16*)p; p += ABF;
  u16* wt    = (u16*)p; p += 7 * WBF;
  u16* qbf   = (u16*)p; p += ABF;
  u16* kbf   = (u16*)p; p += ABF;
  u16* vtb   = (u16*)p; p += ABF;
  u16* ctxb  = (u16*)p; p += ABF;
  float* tmpf = (float*)p; p += AF;
  u16* sobf  = decbf;  // reuse: decoder bf16 dead after layer-1 projections

  u16* WoT  = wt + 6 * 1048576;

  dim3 b256(256);
  convert2_kernel<<<8192, b256, 0, stream>>>(dec, decbf, enc, encbf);
  WP wp;
  wp.w[0] = Wq; wp.w[1] = Wk; wp.w[2] = Wv; wp.w[3] = Wq2;
  wp.w[4] = Wk2; wp.w[5] = Wv2; wp.w[6] = Wo;
  transpose_kernel<<<dim3(16, 16, 7), b256, 0, stream>>>(wp, wt);

  // ---- layer 1 (self-attention on decoder inputs) ----
  qkv3c_kernel<<<dim3(24, 32), b256, 0, stream>>>(
      decbf, decbf, decbf, wt, bq, bk, bv, qbf, kbf, vtb);
  attn_kernel<<<512, 512, 0, stream>>>(qbf, kbf, vtb, tgt_mask, ctxb);
  gemm_proj<<<dim3(8, 32), b256, 0, stream>>>(ctxb, WoT, bo, qbf, tmpf);
  ln_kernel<0><<<4096, b256, 0, stream>>>(tmpf, gamma, beta, nullptr, sobf);
  // ---- layer 2 (cross-attention vs encoder states) ----
  qkv3c_kernel<<<dim3(24, 32), b256, 0, stream>>>(
      sobf, encbf, encbf, wt + 3 * 1048576, bq2, bk2, bv2, qbf, kbf, vtb);
  attn_kernel<<<512, 512, 0, stream>>>(qbf, kbf, vtb, src_mask, ctxb);
  gemm_proj<<<dim3(8, 32), b256, 0, stream>>>(ctxb, WoT, bo, qbf, tmpf);
  ln_kernel<1><<<4096, b256, 0, stream>>>(tmpf, gamma, beta, out, nullptr);
}